// Round 1
// baseline (945.301 us; speedup 1.0000x reference)
//
#include <hip/hip_runtime.h>
#include <cmath>

#define EPS 1e-5f

// ---------------------------------------------------------------------------
// Kernel 1: prep — emb = embedding_sum / max(usage, eps); embT = emb^T;
//           bias[k] = 0.5*|emb_k|^2
// One block per k (256 threads == D).
// ---------------------------------------------------------------------------
__global__ __launch_bounds__(256) void prep_kernel(
    const float* __restrict__ es, const float* __restrict__ usage,
    float* __restrict__ emb, float* __restrict__ embT, float* __restrict__ bias,
    int K, int D)
{
    const int k = blockIdx.x;
    const int d = threadIdx.x;
    const float inv = 1.0f / fmaxf(usage[k], EPS);
    const float v = es[(size_t)k * D + d] * inv;
    emb[(size_t)k * D + d] = v;
    embT[(size_t)d * K + k] = v;   // uncoalesced scatter; 2 MiB total, fine
    float sq = v * v;
    #pragma unroll
    for (int off = 32; off > 0; off >>= 1) sq += __shfl_down(sq, off, 64);
    __shared__ float wsum[4];
    const int lane = threadIdx.x & 63;
    const int wv = threadIdx.x >> 6;
    if (lane == 0) wsum[wv] = sq;
    __syncthreads();
    if (threadIdx.x == 0) bias[k] = 0.5f * (wsum[0] + wsum[1] + wsum[2] + wsum[3]);
}

// ---------------------------------------------------------------------------
// Kernel 2: fused GEMM + argmax.
// score[t,k] = sum_d x[b,d,t]*emb[k,d] - 0.5*|emb_k|^2 ; code = argmax_k
// Tile: Tt=128 (t), Kt=128 (k-chunk), Dt=16. 256 threads = 16x16,
// each computes an 8x8 micro-tile. Running argmax per thread, LDS reduce.
// ---------------------------------------------------------------------------
#define TT 128
#define KT 128
#define DT 16

__global__ __launch_bounds__(256) void argmax_kernel(
    const float* __restrict__ x,     // [B, D, T]
    const float* __restrict__ embT,  // [D, K]
    const float* __restrict__ bias,  // [K]
    float* __restrict__ codes_f,     // [B*T] (output, as float)
    int* __restrict__ codes_i,       // [B*T] (workspace, int)
    int D, int T, int K)
{
    __shared__ float As[DT][TT];      // 8 KB
    __shared__ float Bs[DT][KT];      // 8 KB
    __shared__ float redS[TT][16];    // 8 KB
    __shared__ int   redK[TT][16];    // 8 KB

    const int b   = blockIdx.y;
    const int t0  = blockIdx.x * TT;
    const int tid = threadIdx.x;
    const int tx  = tid & 15;   // k-group
    const int ty  = tid >> 4;   // t-group

    const float* xb = x + (size_t)b * D * T;

    float bestS[8];
    int   bestK[8];
    #pragma unroll
    for (int i = 0; i < 8; ++i) { bestS[i] = -INFINITY; bestK[i] = 0; }

    for (int k0 = 0; k0 < K; k0 += KT) {
        float acc[8][8];
        #pragma unroll
        for (int i = 0; i < 8; ++i)
            #pragma unroll
            for (int j = 0; j < 8; ++j) acc[i][j] = 0.0f;

        for (int d0 = 0; d0 < D; d0 += DT) {
            // Cooperative tile loads: 512 float4 per tile, 2 per thread.
            #pragma unroll
            for (int r = 0; r < 2; ++r) {
                const int q  = tid + r * 256;   // 0..511
                const int dd = q >> 5;          // row 0..15
                const int c4 = q & 31;          // float4 col 0..31
                ((float4*)&As[dd][0])[c4] =
                    *(const float4*)(xb + (size_t)(d0 + dd) * T + t0 + c4 * 4);
                ((float4*)&Bs[dd][0])[c4] =
                    *(const float4*)(embT + (size_t)(d0 + dd) * K + k0 + c4 * 4);
            }
            __syncthreads();

            #pragma unroll
            for (int dd = 0; dd < DT; ++dd) {
                const float4 a0 = ((const float4*)&As[dd][ty * 8])[0];
                const float4 a1 = ((const float4*)&As[dd][ty * 8])[1];
                const float4 b0 = ((const float4*)&Bs[dd][tx * 8])[0];
                const float4 b1 = ((const float4*)&Bs[dd][tx * 8])[1];
                const float av[8] = {a0.x, a0.y, a0.z, a0.w, a1.x, a1.y, a1.z, a1.w};
                const float bv[8] = {b0.x, b0.y, b0.z, b0.w, b1.x, b1.y, b1.z, b1.w};
                #pragma unroll
                for (int i = 0; i < 8; ++i)
                    #pragma unroll
                    for (int j = 0; j < 8; ++j)
                        acc[i][j] += av[i] * bv[j];
            }
            __syncthreads();
        }

        // Epilogue: subtract bias, update running argmax (first-index wins:
        // strict >, and k increases monotonically per thread over chunks).
        #pragma unroll
        for (int j = 0; j < 8; ++j) {
            const int k = k0 + tx * 8 + j;
            const float bj = bias[k];
            #pragma unroll
            for (int i = 0; i < 8; ++i) {
                const float s = acc[i][j] - bj;
                if (s > bestS[i]) { bestS[i] = s; bestK[i] = k; }
            }
        }
    }

    // Cross-thread reduction: t-row ty*8+i has 16 candidates (one per tx).
    #pragma unroll
    for (int i = 0; i < 8; ++i) {
        redS[ty * 8 + i][tx] = bestS[i];
        redK[ty * 8 + i][tx] = bestK[i];
    }
    __syncthreads();
    if (tid < TT) {
        float bs = redS[tid][0];
        int   bk = redK[tid][0];
        #pragma unroll
        for (int j = 1; j < 16; ++j) {
            const float s = redS[tid][j];
            const int   k = redK[tid][j];
            if (s > bs || (s == bs && k < bk)) { bs = s; bk = k; }
        }
        const int t = t0 + tid;
        codes_i[(size_t)b * T + t] = bk;
        codes_f[(size_t)b * T + t] = (float)bk;
    }
}

// ---------------------------------------------------------------------------
// Kernel 3: decode — decoded[b,d,t] = emb[codes[b,t]][d]
// Thread per t; float4 reads of the emb row (L2-resident), coalesced stores.
// ---------------------------------------------------------------------------
__global__ __launch_bounds__(256) void decode_kernel(
    const float* __restrict__ emb,   // [K, D]
    const int* __restrict__ codes,   // [B*T]
    float* __restrict__ out,         // [B, D, T]
    int D, int T)
{
    const int b = blockIdx.y;
    const int t = blockIdx.x * 256 + threadIdx.x;
    const int c = codes[(size_t)b * T + t];
    const float4* e4 = (const float4*)(emb + (size_t)c * D);
    float* ob = out + (size_t)b * D * T + t;
    #pragma unroll 4
    for (int d4 = 0; d4 < 64; ++d4) {   // D/4 == 64
        const float4 v = e4[d4];
        ob[(size_t)(d4 * 4 + 0) * T] = v.x;
        ob[(size_t)(d4 * 4 + 1) * T] = v.y;
        ob[(size_t)(d4 * 4 + 2) * T] = v.z;
        ob[(size_t)(d4 * 4 + 3) * T] = v.w;
    }
}

// ---------------------------------------------------------------------------
extern "C" void kernel_launch(void* const* d_in, const int* in_sizes, int n_in,
                              void* d_out, int out_size, void* d_ws, size_t ws_size,
                              hipStream_t stream) {
    const float* x     = (const float*)d_in[0];   // [B, D, T]
    const float* es    = (const float*)d_in[1];   // [K, D]
    const float* usage = (const float*)d_in[2];   // [K]

    const int K  = in_sizes[2];            // 2048
    const int D  = in_sizes[1] / K;        // 256
    const int T  = 4096;
    const int B  = in_sizes[0] / (D * T);  // 16

    // Workspace layout (floats): emb [K*D] | embT [D*K] | bias [K] | codes_i [B*T]
    float* ws      = (float*)d_ws;
    float* emb     = ws;
    float* embT    = ws + (size_t)K * D;
    float* bias    = ws + (size_t)2 * K * D;
    int*   codes_i = (int*)(ws + (size_t)2 * K * D + K);

    float* codes_f = (float*)d_out;                    // [B*T]
    float* decoded = (float*)d_out + (size_t)B * T;    // [B*D*T]

    prep_kernel<<<K, 256, 0, stream>>>(es, usage, emb, embT, bias, K, D);

    dim3 g2(T / TT, B);
    argmax_kernel<<<g2, 256, 0, stream>>>(x, embT, bias, codes_f, codes_i, D, T, K);

    dim3 g3(T / 256, B);
    decode_kernel<<<g3, 256, 0, stream>>>(emb, codes_i, decoded, D, T);
}

// Round 2
// 485.902 us; speedup vs baseline: 1.9455x; 1.9455x over previous
//
#include <hip/hip_runtime.h>
#include <cmath>

#define EPS 1e-5f
#define TAU 0.03f

// Problem constants (fixed instance)
#define Bn 16
#define Dn 256
#define Tn 4096
#define Kn 2048

typedef __attribute__((ext_vector_type(8))) short bf16x8;
typedef __attribute__((ext_vector_type(4))) float f32x4;

__device__ __forceinline__ unsigned short f2bf(float v, float& back) {
    union { float f; unsigned u; } a; a.f = v;
    unsigned r = a.u + 0x7fffu + ((a.u >> 16) & 1u);   // RNE
    unsigned short h = (unsigned short)(r >> 16);
    union { float f; unsigned u; } b; b.u = ((unsigned)h) << 16;
    back = b.f;
    return h;
}

#define GLOAD_LDS16(gp, lp) __builtin_amdgcn_global_load_lds( \
    (const __attribute__((address_space(1))) unsigned int*)(gp), \
    (__attribute__((address_space(3))) unsigned int*)(lp), 16, 0, 0)

// ---------------------------------------------------------------------------
// Kernel 1: prep — emb = es / max(usage,eps); bf16 hi/mid planes; bias = 0.5|e|^2
// grid = K blocks x 256 threads (D==256). Also zeroes the rescue counter.
// ---------------------------------------------------------------------------
__global__ __launch_bounds__(256) void prep_kernel(
    const float* __restrict__ es, const float* __restrict__ usage,
    float* __restrict__ emb, unsigned short* __restrict__ eh,
    unsigned short* __restrict__ em, float* __restrict__ bias,
    int* __restrict__ counter)
{
    const int k = blockIdx.x;
    const int d = threadIdx.x;
    const float inv = 1.0f / fmaxf(usage[k], EPS);
    const float v = es[(size_t)k * Dn + d] * inv;
    emb[(size_t)k * Dn + d] = v;
    float hb, dummy;
    unsigned short h = f2bf(v, hb);
    eh[(size_t)k * Dn + d] = h;
    em[(size_t)k * Dn + d] = f2bf(v - hb, dummy);
    float sq = v * v;
    #pragma unroll
    for (int off = 32; off > 0; off >>= 1) sq += __shfl_down(sq, off, 64);
    __shared__ float wsum[4];
    const int lane = threadIdx.x & 63;
    const int wv = threadIdx.x >> 6;
    if (lane == 0) wsum[wv] = sq;
    __syncthreads();
    if (threadIdx.x == 0) {
        bias[k] = 0.5f * (wsum[0] + wsum[1] + wsum[2] + wsum[3]);
        if (k == 0) *counter = 0;
    }
}

// ---------------------------------------------------------------------------
// Kernel 2: split-bf16 MFMA GEMM + top-2 argmax per point.
// Block: 256 thr / 4 waves. Tile: TT=128 t, per-block k-range 256 (KSPLIT=8),
// KT=128 per kc pass, BK=32 d-chunk. Wave-tile 32(t) x 128(k): 2x8 mfma tiles.
// Writes (s1, s2, k1) records per (point, ks).
// ---------------------------------------------------------------------------
__global__ __launch_bounds__(256, 3) void gemm_argmax(
    const float* __restrict__ x, const unsigned short* __restrict__ eh,
    const unsigned short* __restrict__ em, const float* __restrict__ bias,
    float4* __restrict__ rec)
{
    __shared__ unsigned short AhS[128 * 32];   // [t][d] with chunk-XOR swizzle, 8 KB
    __shared__ unsigned short AmS[128 * 32];
    __shared__ unsigned short BhS[128 * 32];   // [k][d] lane-linear, 8 KB
    __shared__ unsigned short BmS[128 * 32];

    const int bid   = blockIdx.x;
    const int xcd   = bid & 7;
    const int ks    = (bid >> 3) & 7;
    const int tilid = bid >> 6;
    const int gtile = tilid * 8 + xcd;       // same (b,tt) siblings share an XCD
    const int b     = gtile >> 5;
    const int tt    = gtile & 31;
    const int t0    = tt << 7;
    const int kbase = ks << 8;               // 256 k per block

    const int tid  = threadIdx.x;
    const int lane = tid & 63;
    const int wid  = tid >> 6;

    // per-lane argmax state: 8 t-rows (2 i-tiles x 4 regs)
    float s1[8], s2[8];
    int   k1[8];
    #pragma unroll
    for (int rr = 0; rr < 8; ++rr) { s1[rr] = -INFINITY; s2[rr] = -INFINITY; k1[rr] = 0; }

    // staging thread mapping: d-pair dp = tid>>4 (d=2dp,2dp+1), t-octet tseg = tid&15
    const int dp   = tid >> 4;
    const int tseg = tid & 15;

    for (int kc = 0; kc < 2; ++kc) {
        const int k0 = kbase + kc * 128;

        f32x4 acc[2][8];
        #pragma unroll
        for (int i = 0; i < 2; ++i)
            #pragma unroll
            for (int j = 0; j < 8; ++j) acc[i][j] = (f32x4){0.f, 0.f, 0.f, 0.f};

        for (int dstep = 0; dstep < 8; ++dstep) {
            const int d0 = dstep * 32;
            __syncthreads();   // protect LDS from previous stage's readers

            // ---- A stage: fp32 global -> bf16 hi/mid transpose into LDS ----
            {
                const float* r0 = x + ((size_t)(b * Dn + d0 + dp * 2)) * Tn + t0 + tseg * 8;
                const float4 a0 = *(const float4*)(r0);
                const float4 a1 = *(const float4*)(r0 + 4);
                const float4 c0 = *(const float4*)(r0 + Tn);
                const float4 c1 = *(const float4*)(r0 + Tn + 4);
                const float v0[8] = {a0.x, a0.y, a0.z, a0.w, a1.x, a1.y, a1.z, a1.w};
                const float v1[8] = {c0.x, c0.y, c0.z, c0.w, c1.x, c1.y, c1.z, c1.w};
                unsigned int* AhW = (unsigned int*)AhS;
                unsigned int* AmW = (unsigned int*)AmS;
                #pragma unroll
                for (int e = 0; e < 8; ++e) {
                    const int t = tseg * 8 + e;
                    float hb0, hb1, dm;
                    const unsigned short h0 = f2bf(v0[e], hb0);
                    const unsigned short m0 = f2bf(v0[e] - hb0, dm);
                    const unsigned short h1 = f2bf(v1[e], hb1);
                    const unsigned short m1 = f2bf(v1[e] - hb1, dm);
                    // word = t*16 + swizzled_chunk*4 + (dp&3); chunk = dp>>2
                    const int word = (t << 4) + ((((dp >> 2) ^ ((t >> 3) & 3))) << 2) + (dp & 3);
                    AhW[word] = (unsigned)h0 | ((unsigned)h1 << 16);
                    AmW[word] = (unsigned)m0 | ((unsigned)m1 << 16);
                }
            }

            // ---- B stage: bf16 planes via global_load_lds width 16 ----
            #pragma unroll
            for (int r = 0; r < 2; ++r) {
                const int c    = ((r * 4 + wid) << 6) + lane;   // chunk 0..511
                const int krow = c >> 2;
                const int doff = (c & 3) << 3;
                const size_t goff = ((size_t)(k0 + krow) << 8) + d0 + doff;
                const int lbase = (r * 4 + wid) << 9;           // elements
                GLOAD_LDS16(eh + goff, BhS + lbase);
                GLOAD_LDS16(em + goff, BmS + lbase);
            }
            __syncthreads();

            // ---- compute: 2x8 tiles x 3 products ----
            bf16x8 ah[2], am[2];
            #pragma unroll
            for (int i = 0; i < 2; ++i) {
                const int t   = (wid << 5) + (i << 4) + (lane & 15);
                const int off = (t << 5) + ((((lane >> 4) ^ ((t >> 3) & 3))) << 3);
                ah[i] = *(const bf16x8*)(AhS + off);
                am[i] = *(const bf16x8*)(AmS + off);
            }
            #pragma unroll
            for (int j = 0; j < 8; ++j) {
                const int kl  = (j << 4) + (lane & 15);
                const int off = (kl << 5) + ((lane >> 4) << 3);
                const bf16x8 bh = *(const bf16x8*)(BhS + off);
                const bf16x8 bm = *(const bf16x8*)(BmS + off);
                #pragma unroll
                for (int i = 0; i < 2; ++i) {
                    acc[i][j] = __builtin_amdgcn_mfma_f32_16x16x32_bf16(ah[i], bh, acc[i][j], 0, 0, 0);
                    acc[i][j] = __builtin_amdgcn_mfma_f32_16x16x32_bf16(ah[i], bm, acc[i][j], 0, 0, 0);
                    acc[i][j] = __builtin_amdgcn_mfma_f32_16x16x32_bf16(am[i], bh, acc[i][j], 0, 0, 0);
                }
            }
        }

        // ---- epilogue for this kc: subtract bias, update top-2 (k ascending) ----
        float bb[8];
        #pragma unroll
        for (int j = 0; j < 8; ++j) bb[j] = bias[k0 + j * 16 + (lane & 15)];
        #pragma unroll
        for (int j = 0; j < 8; ++j) {
            const int kg = k0 + j * 16 + (lane & 15);
            #pragma unroll
            for (int i = 0; i < 2; ++i) {
                #pragma unroll
                for (int r = 0; r < 4; ++r) {
                    const float s = acc[i][j][r] - bb[j];
                    const int rr = i * 4 + r;
                    if (s > s1[rr]) { s2[rr] = s1[rr]; s1[rr] = s; k1[rr] = kg; }
                    else if (s > s2[rr]) s2[rr] = s;
                }
            }
        }
    }

    // ---- butterfly merge across the 16 lanes sharing each t-row ----
    #pragma unroll
    for (int m = 1; m <= 8; m <<= 1) {
        #pragma unroll
        for (int rr = 0; rr < 8; ++rr) {
            const float os1 = __shfl_xor(s1[rr], m);
            const float os2 = __shfl_xor(s2[rr], m);
            const int   ok1 = __shfl_xor(k1[rr], m);
            const bool take = (os1 > s1[rr]) || (os1 == s1[rr] && ok1 < k1[rr]);
            const float ns2 = take ? fmaxf(s1[rr], os2) : fmaxf(s2[rr], os1);
            if (take) { s1[rr] = os1; k1[rr] = ok1; }
            s2[rr] = ns2;
        }
    }

    if ((lane & 15) == 0) {
        const int lg = lane >> 4;
        #pragma unroll
        for (int rr = 0; rr < 8; ++rr) {
            const int i = rr >> 2, r = rr & 3;
            const int row = (wid << 5) + (i << 4) + (lg << 2) + r;
            const size_t p = (size_t)b * Tn + t0 + row;
            rec[p * 8 + ks] = make_float4(s1[rr], s2[rr], __int_as_float(k1[rr]), 0.f);
        }
    }
}

// ---------------------------------------------------------------------------
// Kernel 3: merge 8 k-partition records per point; emit codes + rescue list.
// ---------------------------------------------------------------------------
__global__ __launch_bounds__(256) void merge_kernel(
    const float4* __restrict__ rec, int* __restrict__ codes_i,
    float* __restrict__ codes_f, int* __restrict__ list, int* __restrict__ counter)
{
    const int p = blockIdx.x * 256 + threadIdx.x;
    const float4* r = rec + ((size_t)p << 3);
    float4 v = r[0];
    float s1 = v.x, s2 = v.y;
    int k1 = __float_as_int(v.z);
    #pragma unroll
    for (int ks = 1; ks < 8; ++ks) {
        const float4 w = r[ks];
        if (w.x > s1) { s2 = fmaxf(s1, w.y); s1 = w.x; k1 = __float_as_int(w.z); }
        else          { s2 = fmaxf(s2, w.x); }
    }
    codes_i[p] = k1;
    codes_f[p] = (float)k1;
    if (s1 - s2 < TAU) {
        const int idx = atomicAdd(counter, 1);
        list[idx] = p;
    }
}

// ---------------------------------------------------------------------------
// Kernel 4: exact fp32 rescore for margin-uncertified points (8 per group).
// ---------------------------------------------------------------------------
__global__ __launch_bounds__(256) void rescue_kernel(
    const float* __restrict__ x, const float* __restrict__ emb,
    const float* __restrict__ bias, const int* __restrict__ list,
    const int* __restrict__ counter, int* __restrict__ codes_i,
    float* __restrict__ codes_f)
{
    __shared__ float xv[8][256];
    __shared__ int plist[8];
    __shared__ float rs[8][4];
    __shared__ int rk[8][4];
    const int tid = threadIdx.x, lane = tid & 63, wid = tid >> 6;
    const int count = *counter;
    for (int g = blockIdx.x; g * 8 < count; g += gridDim.x) {
        const int base = g * 8;
        const int npts = min(8, count - base);
        __syncthreads();
        if (tid < npts) plist[tid] = list[base + tid];
        __syncthreads();
        for (int pi = 0; pi < npts; ++pi) {
            const int p = plist[pi];
            const int bb = p >> 12, t = p & 4095;
            xv[pi][tid] = x[(((size_t)bb << 8) + tid) * Tn + t];
        }
        __syncthreads();
        float bs[8]; int bk[8];
        #pragma unroll
        for (int pi = 0; pi < 8; ++pi) { bs[pi] = -INFINITY; bk[pi] = 0; }
        for (int kk = tid; kk < Kn; kk += 256) {
            const float4* er = (const float4*)(emb + ((size_t)kk << 8));
            float acc[8];
            #pragma unroll
            for (int pi = 0; pi < 8; ++pi) acc[pi] = 0.f;
            for (int dc = 0; dc < 64; ++dc) {
                const float4 e4 = er[dc];
                #pragma unroll
                for (int pi = 0; pi < 8; ++pi) {
                    const float4 xw = *(const float4*)&xv[pi][dc << 2];
                    acc[pi] += e4.x * xw.x + e4.y * xw.y + e4.z * xw.z + e4.w * xw.w;
                }
            }
            const float bv = bias[kk];
            #pragma unroll
            for (int pi = 0; pi < 8; ++pi) {
                const float s = acc[pi] - bv;
                if (s > bs[pi]) { bs[pi] = s; bk[pi] = kk; }
            }
        }
        #pragma unroll
        for (int off = 1; off < 64; off <<= 1) {
            #pragma unroll
            for (int pi = 0; pi < 8; ++pi) {
                const float os = __shfl_xor(bs[pi], off);
                const int   ok = __shfl_xor(bk[pi], off);
                if (os > bs[pi] || (os == bs[pi] && ok < bk[pi])) { bs[pi] = os; bk[pi] = ok; }
            }
        }
        if (lane == 0) {
            #pragma unroll
            for (int pi = 0; pi < 8; ++pi) { rs[pi][wid] = bs[pi]; rk[pi][wid] = bk[pi]; }
        }
        __syncthreads();
        if (tid < npts) {
            float fs = rs[tid][0]; int fk = rk[tid][0];
            #pragma unroll
            for (int w = 1; w < 4; ++w) {
                const float os = rs[tid][w]; const int ok = rk[tid][w];
                if (os > fs || (os == fs && ok < fk)) { fs = os; fk = ok; }
            }
            const int p = plist[tid];
            codes_i[p] = fk;
            codes_f[p] = (float)fk;
        }
    }
}

// ---------------------------------------------------------------------------
// Kernel 5: decode — decoded[b,d,t] = emb[codes[b,t]][d]
// ---------------------------------------------------------------------------
__global__ __launch_bounds__(256) void decode_kernel(
    const float* __restrict__ emb, const int* __restrict__ codes,
    float* __restrict__ out)
{
    const int b = blockIdx.y;
    const int t = blockIdx.x * 256 + threadIdx.x;
    const int c = codes[(size_t)b * Tn + t];
    const float4* e4 = (const float4*)(emb + (size_t)c * Dn);
    float* ob = out + (size_t)b * Dn * Tn + t;
    #pragma unroll 4
    for (int d4 = 0; d4 < 64; ++d4) {
        const float4 v = e4[d4];
        ob[(size_t)(d4 * 4 + 0) * Tn] = v.x;
        ob[(size_t)(d4 * 4 + 1) * Tn] = v.y;
        ob[(size_t)(d4 * 4 + 2) * Tn] = v.z;
        ob[(size_t)(d4 * 4 + 3) * Tn] = v.w;
    }
}

// ---------------------------------------------------------------------------
extern "C" void kernel_launch(void* const* d_in, const int* in_sizes, int n_in,
                              void* d_out, int out_size, void* d_ws, size_t ws_size,
                              hipStream_t stream) {
    const float* x     = (const float*)d_in[0];   // [B, D, T]
    const float* es    = (const float*)d_in[1];   // [K, D]
    const float* usage = (const float*)d_in[2];   // [K]

    // ws layout (byte offsets, all 16-aligned)
    char* ws = (char*)d_ws;
    float*          emb     = (float*)(ws + 0);               // 2 MiB
    float*          bias    = (float*)(ws + 2097152);         // 8 KB
    unsigned short* eh      = (unsigned short*)(ws + 2105344);// 1 MiB
    unsigned short* em      = (unsigned short*)(ws + 3153920);// 1 MiB
    float4*         rec     = (float4*)(ws + 4202496);        // 8 MiB
    int*            codes_i = (int*)(ws + 12591104);          // 256 KB
    int*            list    = (int*)(ws + 12853248);          // 256 KB
    int*            counter = (int*)(ws + 13115392);          // 4 B

    float* codes_f = (float*)d_out;                      // [B*T]
    float* decoded = (float*)d_out + (size_t)Bn * Tn;    // [B*D*T]

    prep_kernel<<<Kn, 256, 0, stream>>>(es, usage, emb, eh, em, bias, counter);
    gemm_argmax<<<4096, 256, 0, stream>>>(x, eh, em, bias, rec);
    merge_kernel<<<(Bn * Tn) / 256, 256, 0, stream>>>(rec, codes_i, codes_f, list, counter);
    rescue_kernel<<<512, 256, 0, stream>>>(x, emb, bias, list, counter, codes_i, codes_f);
    dim3 g5(Tn / 256, Bn);
    decode_kernel<<<g5, 256, 0, stream>>>(emb, codes_i, decoded);
}

// Round 3
// 437.349 us; speedup vs baseline: 2.1614x; 1.1110x over previous
//
#include <hip/hip_runtime.h>
#include <cmath>

#define EPS 1e-5f
#define TAU 0.01f

// Problem constants (fixed instance)
#define Bn 16
#define Dn 256
#define Tn 4096
#define Kn 2048

typedef unsigned short ushort_t;
typedef __attribute__((ext_vector_type(8))) short bf16x8;
typedef __attribute__((ext_vector_type(4))) float f32x4;

__device__ __forceinline__ unsigned short f2bf(float v, float& back) {
    union { float f; unsigned u; } a; a.f = v;
    unsigned r = a.u + 0x7fffu + ((a.u >> 16) & 1u);   // RNE
    unsigned short h = (unsigned short)(r >> 16);
    union { float f; unsigned u; } b; b.u = ((unsigned)h) << 16;
    back = b.f;
    return h;
}

#define GLOAD_LDS16(gp, lp) __builtin_amdgcn_global_load_lds( \
    (const __attribute__((address_space(1))) unsigned int*)(gp), \
    (__attribute__((address_space(3))) unsigned int*)(lp), 16, 0, 0)

// ---------------------------------------------------------------------------
// Kernel 1: prep — emb = es / max(usage,eps); bf16 hi/mid planes; bias = 0.5|e|^2
// ---------------------------------------------------------------------------
__global__ __launch_bounds__(256) void prep_kernel(
    const float* __restrict__ es, const float* __restrict__ usage,
    float* __restrict__ emb, ushort_t* __restrict__ eh,
    ushort_t* __restrict__ em, float* __restrict__ bias,
    int* __restrict__ counter)
{
    const int k = blockIdx.x;
    const int d = threadIdx.x;
    const float inv = 1.0f / fmaxf(usage[k], EPS);
    const float v = es[(size_t)k * Dn + d] * inv;
    emb[(size_t)k * Dn + d] = v;
    float hb, dummy;
    unsigned short h = f2bf(v, hb);
    eh[(size_t)k * Dn + d] = h;
    em[(size_t)k * Dn + d] = f2bf(v - hb, dummy);
    float sq = v * v;
    #pragma unroll
    for (int off = 32; off > 0; off >>= 1) sq += __shfl_down(sq, off, 64);
    __shared__ float wsum[4];
    const int lane = threadIdx.x & 63;
    const int wv = threadIdx.x >> 6;
    if (lane == 0) wsum[wv] = sq;
    __syncthreads();
    if (threadIdx.x == 0) {
        bias[k] = 0.5f * (wsum[0] + wsum[1] + wsum[2] + wsum[3]);
        if (k == 0) *counter = 0;
    }
}

// ---------------------------------------------------------------------------
// Kernel 2: xsplit — x[b][d][t] fp32 -> xh/xm[b][t][d] bf16 (hi/mid split).
// Tile 32d x 64t per block; LDS transpose with +1 pad (65) to spread banks.
// ---------------------------------------------------------------------------
__global__ __launch_bounds__(256) void xsplit_kernel(
    const float* __restrict__ x, ushort_t* __restrict__ xh,
    ushort_t* __restrict__ xm)
{
    __shared__ float tile[32 * 65];
    const int t0 = blockIdx.x * 64;
    const int d0 = blockIdx.y * 32;
    const int b  = blockIdx.z;
    const int tid = threadIdx.x;

    // read phase: (dl, tq) — 8 floats along t per thread
    {
        const int dl = tid >> 3, tq = tid & 7;
        const float* src = x + ((size_t)(b * Dn + d0 + dl)) * Tn + t0 + tq * 8;
        const float4 a = *(const float4*)src;
        const float4 c = *(const float4*)(src + 4);
        float* row = &tile[dl * 65 + tq * 8];
        row[0] = a.x; row[1] = a.y; row[2] = a.z; row[3] = a.w;
        row[4] = c.x; row[5] = c.y; row[6] = c.z; row[7] = c.w;
    }
    __syncthreads();
    // write phase: (t_l, dq) — 8 d-consecutive elems -> 16 B store per plane
    {
        const int t_l = tid >> 2, dq = tid & 3;
        unsigned wh[4], wm[4];
        #pragma unroll
        for (int i = 0; i < 4; ++i) {
            const float a = tile[(dq * 8 + 2 * i) * 65 + t_l];
            const float c = tile[(dq * 8 + 2 * i + 1) * 65 + t_l];
            float hb0, hb1, dm;
            const unsigned short h0 = f2bf(a, hb0);
            const unsigned short m0 = f2bf(a - hb0, dm);
            const unsigned short h1 = f2bf(c, hb1);
            const unsigned short m1 = f2bf(c - hb1, dm);
            wh[i] = (unsigned)h0 | ((unsigned)h1 << 16);
            wm[i] = (unsigned)m0 | ((unsigned)m1 << 16);
        }
        const size_t o = ((size_t)(b * Tn + t0 + t_l)) * Dn + d0 + dq * 8;
        *(uint4*)(xh + o) = make_uint4(wh[0], wh[1], wh[2], wh[3]);
        *(uint4*)(xm + o) = make_uint4(wm[0], wm[1], wm[2], wm[3]);
    }
}

// ---------------------------------------------------------------------------
// Kernel 3: split-bf16 MFMA GEMM + top-2 argmax. Both operands staged via
// global_load_lds width 16 from prepacked bf16 planes (no staging VALU).
// Block: 256 thr / 4 waves. TT=128 t, k-range 256 (KSPLIT=8), kc=128, BK=32.
// ---------------------------------------------------------------------------
__global__ __launch_bounds__(256, 3) void gemm_argmax(
    const ushort_t* __restrict__ xh, const ushort_t* __restrict__ xm,
    const ushort_t* __restrict__ eh, const ushort_t* __restrict__ em,
    const float* __restrict__ bias, float4* __restrict__ rec)
{
    __shared__ ushort_t AhS[128 * 32];   // [t][d-window 32], 64 B rows, 8 KB
    __shared__ ushort_t AmS[128 * 32];
    __shared__ ushort_t BhS[128 * 32];   // [k][d-window 32]
    __shared__ ushort_t BmS[128 * 32];

    const int bid   = blockIdx.x;
    const int xcd   = bid & 7;
    const int ks    = (bid >> 3) & 7;
    const int tilid = bid >> 6;
    const int gtile = tilid * 8 + xcd;   // ks-siblings of one (b,tt) share an XCD
    const int b     = gtile >> 5;
    const int tt    = gtile & 31;
    const int t0    = tt << 7;
    const int kbase = ks << 8;

    const int tid  = threadIdx.x;
    const int lane = tid & 63;
    const int wid  = tid >> 6;

    const size_t bTt0 = (size_t)b * Tn + t0;

    // frag read offsets (shorts)
    const int aoff0 = (wid * 32 + (lane & 15)) * 32 + (lane >> 4) * 8;
    const int aoff1 = aoff0 + 16 * 32;
    const int boffL = (lane & 15) * 32 + (lane >> 4) * 8;

    float s1[8], s2[8];
    int   k1[8];
    #pragma unroll
    for (int rr = 0; rr < 8; ++rr) { s1[rr] = -INFINITY; s2[rr] = -INFINITY; k1[rr] = 0; }

    for (int kc = 0; kc < 2; ++kc) {
        const int k0 = kbase + kc * 128;

        f32x4 acc[2][8];
        #pragma unroll
        for (int i = 0; i < 2; ++i)
            #pragma unroll
            for (int j = 0; j < 8; ++j) acc[i][j] = (f32x4){0.f, 0.f, 0.f, 0.f};

        for (int dstep = 0; dstep < 8; ++dstep) {
            const int d0 = dstep * 32;
            __syncthreads();   // previous stage's readers done

            #pragma unroll
            for (int r = 0; r < 2; ++r) {
                const int cb = (r * 4 + wid) << 6;        // chunk base (wave-uniform)
                const int c  = cb + lane;                 // 0..511
                const int row = c >> 2;
                const int doff = d0 + (c & 3) * 8;
                const size_t ao = (bTt0 + row) * Dn + doff;
                const size_t bo = ((size_t)(k0 + row)) * Dn + doff;
                const int lb = cb * 8;                    // shorts
                GLOAD_LDS16(xh + ao, AhS + lb);
                GLOAD_LDS16(xm + ao, AmS + lb);
                GLOAD_LDS16(eh + bo, BhS + lb);
                GLOAD_LDS16(em + bo, BmS + lb);
            }
            __syncthreads();   // barrier drains vmcnt

            const bf16x8 ah0 = *(const bf16x8*)(AhS + aoff0);
            const bf16x8 am0 = *(const bf16x8*)(AmS + aoff0);
            const bf16x8 ah1 = *(const bf16x8*)(AhS + aoff1);
            const bf16x8 am1 = *(const bf16x8*)(AmS + aoff1);
            #pragma unroll
            for (int j = 0; j < 8; ++j) {
                const int off = (j << 9) + boffL;         // j*16 rows * 32 shorts
                const bf16x8 bh = *(const bf16x8*)(BhS + off);
                const bf16x8 bm = *(const bf16x8*)(BmS + off);
                acc[0][j] = __builtin_amdgcn_mfma_f32_16x16x32_bf16(ah0, bh, acc[0][j], 0, 0, 0);
                acc[0][j] = __builtin_amdgcn_mfma_f32_16x16x32_bf16(ah0, bm, acc[0][j], 0, 0, 0);
                acc[0][j] = __builtin_amdgcn_mfma_f32_16x16x32_bf16(am0, bh, acc[0][j], 0, 0, 0);
                acc[1][j] = __builtin_amdgcn_mfma_f32_16x16x32_bf16(ah1, bh, acc[1][j], 0, 0, 0);
                acc[1][j] = __builtin_amdgcn_mfma_f32_16x16x32_bf16(ah1, bm, acc[1][j], 0, 0, 0);
                acc[1][j] = __builtin_amdgcn_mfma_f32_16x16x32_bf16(am1, bh, acc[1][j], 0, 0, 0);
            }
        }

        // epilogue: subtract bias, update running top-2 (k ascending per lane)
        #pragma unroll
        for (int j = 0; j < 8; ++j) {
            const int kg = k0 + j * 16 + (lane & 15);
            const float bj = bias[kg];
            #pragma unroll
            for (int i = 0; i < 2; ++i) {
                #pragma unroll
                for (int r = 0; r < 4; ++r) {
                    const float s = acc[i][j][r] - bj;
                    const int rr = i * 4 + r;
                    if (s > s1[rr]) { s2[rr] = s1[rr]; s1[rr] = s; k1[rr] = kg; }
                    else if (s > s2[rr]) s2[rr] = s;
                }
            }
        }
    }

    // butterfly merge across the 16 lanes sharing each t-row
    #pragma unroll
    for (int m = 1; m <= 8; m <<= 1) {
        #pragma unroll
        for (int rr = 0; rr < 8; ++rr) {
            const float os1 = __shfl_xor(s1[rr], m);
            const float os2 = __shfl_xor(s2[rr], m);
            const int   ok1 = __shfl_xor(k1[rr], m);
            const bool take = (os1 > s1[rr]) || (os1 == s1[rr] && ok1 < k1[rr]);
            const float ns2 = take ? fmaxf(s1[rr], os2) : fmaxf(s2[rr], os1);
            if (take) { s1[rr] = os1; k1[rr] = ok1; }
            s2[rr] = ns2;
        }
    }

    if ((lane & 15) == 0) {
        const int lg = lane >> 4;
        #pragma unroll
        for (int rr = 0; rr < 8; ++rr) {
            const int i = rr >> 2, r = rr & 3;
            const int row = (wid << 5) + (i << 4) + (lg << 2) + r;
            const size_t p = (size_t)b * Tn + t0 + row;
            rec[p * 8 + ks] = make_float4(s1[rr], s2[rr], __int_as_float(k1[rr]), 0.f);
        }
    }
}

// ---------------------------------------------------------------------------
// Kernel 4: merge 8 k-partition records per point; emit codes + rescue list.
// ---------------------------------------------------------------------------
__global__ __launch_bounds__(256) void merge_kernel(
    const float4* __restrict__ rec, int* __restrict__ codes_i,
    float* __restrict__ codes_f, int* __restrict__ list, int* __restrict__ counter)
{
    const int p = blockIdx.x * 256 + threadIdx.x;
    const float4* r = rec + ((size_t)p << 3);
    float4 v = r[0];
    float s1 = v.x, s2 = v.y;
    int k1 = __float_as_int(v.z);
    #pragma unroll
    for (int ks = 1; ks < 8; ++ks) {
        const float4 w = r[ks];
        if (w.x > s1) { s2 = fmaxf(s1, w.y); s1 = w.x; k1 = __float_as_int(w.z); }
        else          { s2 = fmaxf(s2, w.x); }
    }
    codes_i[p] = k1;
    codes_f[p] = (float)k1;
    if (s1 - s2 < TAU) {
        const int idx = atomicAdd(counter, 1);
        list[idx] = p;
    }
}

// ---------------------------------------------------------------------------
// Kernel 5: exact fp32 rescore, one block per uncertain point (FMA-bound:
// dc-outer, 8 k-rows per thread in registers, LDS x broadcast).
// ---------------------------------------------------------------------------
__global__ __launch_bounds__(256) void rescue_kernel(
    const float* __restrict__ x, const float* __restrict__ emb,
    const float* __restrict__ bias, const int* __restrict__ list,
    const int* __restrict__ counter, int* __restrict__ codes_i,
    float* __restrict__ codes_f)
{
    __shared__ float xv[256];
    __shared__ float rs[4];
    __shared__ int   rk[4];
    const int tid = threadIdx.x, lane = tid & 63, wid = tid >> 6;
    const int count = *counter;
    for (int idx = blockIdx.x; idx < count; idx += gridDim.x) {
        __syncthreads();   // protect xv/rs/rk from previous iteration
        const int p = list[idx];
        const int bb = p >> 12, t = p & 4095;
        xv[tid] = x[((size_t)bb * Dn + tid) * Tn + t];
        __syncthreads();

        float acc[8];
        #pragma unroll
        for (int s = 0; s < 8; ++s) acc[s] = 0.f;
        const float4* e0 = (const float4*)emb + (size_t)tid * 64;
        for (int dc = 0; dc < 64; ++dc) {
            const float4 xw = *(const float4*)&xv[dc << 2];
            #pragma unroll
            for (int s = 0; s < 8; ++s) {
                const float4 e4 = e0[(size_t)s * 16384 + dc];  // 256 rows * 64 f4
                acc[s] += e4.x * xw.x + e4.y * xw.y + e4.z * xw.z + e4.w * xw.w;
            }
        }
        float bs = -INFINITY; int bk = 0;
        #pragma unroll
        for (int s = 0; s < 8; ++s) {
            const int kk = tid + (s << 8);
            const float sc = acc[s] - bias[kk];
            if (sc > bs) { bs = sc; bk = kk; }   // kk ascending per thread
        }
        #pragma unroll
        for (int off = 1; off < 64; off <<= 1) {
            const float os = __shfl_xor(bs, off);
            const int   ok = __shfl_xor(bk, off);
            if (os > bs || (os == bs && ok < bk)) { bs = os; bk = ok; }
        }
        if (lane == 0) { rs[wid] = bs; rk[wid] = bk; }
        __syncthreads();
        if (tid == 0) {
            float fs = rs[0]; int fk = rk[0];
            #pragma unroll
            for (int w = 1; w < 4; ++w) {
                if (rs[w] > fs || (rs[w] == fs && rk[w] < fk)) { fs = rs[w]; fk = rk[w]; }
            }
            codes_i[p] = fk;
            codes_f[p] = (float)fk;
        }
    }
}

// ---------------------------------------------------------------------------
// Kernel 6: decode — decoded[b,d,t] = emb[codes[b,t]][d]
// ---------------------------------------------------------------------------
__global__ __launch_bounds__(256) void decode_kernel(
    const float* __restrict__ emb, const int* __restrict__ codes,
    float* __restrict__ out)
{
    const int b = blockIdx.y;
    const int t = blockIdx.x * 256 + threadIdx.x;
    const int c = codes[(size_t)b * Tn + t];
    const float4* e4 = (const float4*)(emb + (size_t)c * Dn);
    float* ob = out + (size_t)b * Dn * Tn + t;
    #pragma unroll 4
    for (int d4 = 0; d4 < 64; ++d4) {
        const float4 v = e4[d4];
        ob[(size_t)(d4 * 4 + 0) * Tn] = v.x;
        ob[(size_t)(d4 * 4 + 1) * Tn] = v.y;
        ob[(size_t)(d4 * 4 + 2) * Tn] = v.z;
        ob[(size_t)(d4 * 4 + 3) * Tn] = v.w;
    }
}

// ---------------------------------------------------------------------------
extern "C" void kernel_launch(void* const* d_in, const int* in_sizes, int n_in,
                              void* d_out, int out_size, void* d_ws, size_t ws_size,
                              hipStream_t stream) {
    const float* x     = (const float*)d_in[0];   // [B, D, T]
    const float* es    = (const float*)d_in[1];   // [K, D]
    const float* usage = (const float*)d_in[2];   // [K]

    // ws layout (byte offsets, 16-aligned) — ~13.1 MiB, same footprint as R2
    char* ws = (char*)d_ws;
    float*    emb     = (float*)(ws + 0);                // 2 MiB
    float*    bias    = (float*)(ws + 2097152);          // 8 KB
    ushort_t* eh      = (ushort_t*)(ws + 2105344);       // 1 MiB
    ushort_t* em      = (ushort_t*)(ws + 3153920);       // 1 MiB
    float4*   rec     = (float4*)(ws + 4202496);         // 8 MiB
    int*      codes_i = (int*)(ws + 12591104);           // 256 KB
    int*      list    = (int*)(ws + 12853248);           // 256 KB
    int*      counter = (int*)(ws + 13115392);           // 4 B

    float* codes_f = (float*)d_out;                      // [B*T]
    float* decoded = (float*)d_out + (size_t)Bn * Tn;    // [B*D*T], 64 MiB

    // xh/xm live in the decoded region (exactly 64 MiB); decode overwrites at
    // the end, after gemm has consumed them. Stream order guarantees safety.
    ushort_t* xh = (ushort_t*)decoded;                   // 32 MiB
    ushort_t* xm = xh + (size_t)Bn * Tn * Dn;            // 32 MiB

    prep_kernel<<<Kn, 256, 0, stream>>>(es, usage, emb, eh, em, bias, counter);

    dim3 gx(Tn / 64, Dn / 32, Bn);
    xsplit_kernel<<<gx, 256, 0, stream>>>(x, xh, xm);

    gemm_argmax<<<4096, 256, 0, stream>>>(xh, xm, eh, em, bias, rec);

    merge_kernel<<<(Bn * Tn) / 256, 256, 0, stream>>>(rec, codes_i, codes_f, list, counter);

    rescue_kernel<<<512, 256, 0, stream>>>(x, emb, bias, list, counter, codes_i, codes_f);

    dim3 g6(Tn / 256, Bn);
    decode_kernel<<<g6, 256, 0, stream>>>(emb, codes_i, decoded);
}